// Round 7
// baseline (474.615 us; speedup 1.0000x reference)
//
#include <hip/hip_runtime.h>

#define NN 50000
#define NE 800000
#define NG 64
#define HID 128
#define DOUT 64
#define LN_EPS 1e-5f
#define NBUK 391   // ceil(50000/128) coarse buckets of 128 dst nodes
#define BCAP 3072  // capacity per bucket
#define EPB 8192   // edges per k_bucket block

typedef unsigned int uint32;
typedef unsigned short ushort16;
typedef __attribute__((ext_vector_type(8))) short bf16x8;
typedef __attribute__((ext_vector_type(4))) float f32x4;

// ---- bf16 helpers (RNE pack, cheap unpack) ----
__device__ inline ushort16 f2bf(float f) {
  uint32 u = __float_as_uint(f);
  u += 0x7fffu + ((u >> 16) & 1u);
  return (ushort16)(u >> 16);
}
__device__ inline uint32 pack2(float x, float y) {
  return (uint32)f2bf(x) | ((uint32)f2bf(y) << 16);
}
__device__ inline float bflo(uint32 p) { return __uint_as_float(p << 16); }
__device__ inline float bfhi(uint32 p) { return __uint_as_float(p & 0xffff0000u); }

__global__ __launch_bounds__(256) void k_zero_f(float* p, int n) {
  int i = blockIdx.x * 256 + threadIdx.x;
  if (i < n) p[i] = 0.f;
}

// ---------------- CSR build: bucket counting sort ----------------
__global__ __launch_bounds__(256) void k_init_bcur(int* __restrict__ bcur) {
  int i = blockIdx.x * 256 + threadIdx.x;
  if (i < NBUK) bcur[i] = i * BCAP;
}

__global__ __launch_bounds__(1024) void k_bucket(const int* __restrict__ src,
                                                 const int* __restrict__ dst,
                                                 const float* __restrict__ ea,
                                                 int* __restrict__ bcur,
                                                 uint2* __restrict__ tmp, int e) {
  __shared__ int hist[NBUK], lbase[NBUK], lcur[NBUK];
  int t = threadIdx.x;
  for (int i = t; i < NBUK; i += 1024) {
    hist[i] = 0;
    lcur[i] = 0;
  }
  __syncthreads();
  int base_e = blockIdx.x * EPB;
  int dstv[EPB / 1024];
#pragma unroll
  for (int k = 0; k < EPB / 1024; k++) {
    int i = base_e + k * 1024 + t;
    int d = (i < e) ? dst[i] : -1;
    dstv[k] = d;
    if (d >= 0) atomicAdd(&hist[d >> 7], 1);
  }
  __syncthreads();
  for (int i = t; i < NBUK; i += 1024) {
    int c = hist[i];
    int b = 0;
    if (c > 0) b = atomicAdd(&bcur[i], c);
    lbase[i] = b;
  }
  __syncthreads();
#pragma unroll
  for (int k = 0; k < EPB / 1024; k++) {
    int i = base_e + k * 1024 + t;
    int d = dstv[k];
    if (d >= 0) {
      int b = d >> 7;
      int r = atomicAdd(&lcur[b], 1);
      int pos = lbase[b] + r;
      if (pos < (b + 1) * BCAP) {
        uint2 rec;
        rec.x = (uint32)(src[i] & 0xffff) | ((uint32)(d & 127) << 16);
        rec.y = __float_as_uint(ea[i]);
        tmp[pos] = rec;
      }
    }
  }
}

__global__ __launch_bounds__(512) void k_bscan(const int* __restrict__ bcur,
                                               int* __restrict__ bbase,
                                               int* __restrict__ rowptr) {
  __shared__ int s[512];
  int t = threadIdx.x;
  int v = 0;
  if (t < NBUK) {
    v = bcur[t] - t * BCAP;
    if (v > BCAP) v = BCAP;
  }
  s[t] = v;
  __syncthreads();
  for (int off = 1; off < 512; off <<= 1) {
    int x = (t >= off) ? s[t - off] : 0;
    __syncthreads();
    s[t] += x;
    __syncthreads();
  }
  if (t < NBUK) bbase[t] = s[t] - v;
  if (t == 511) {
    bbase[NBUK] = s[511];
    rowptr[NN] = s[511];
  }
}

// emits csrc (4B src index) + e_msg (uint2: src, edge_attr) + rowptr/dis/invc
__global__ __launch_bounds__(256) void k_bsort(const uint2* __restrict__ tmp,
                                               const int* __restrict__ bcur,
                                               const int* __restrict__ bbase,
                                               int* __restrict__ rowptr,
                                               int* __restrict__ csrc,
                                               uint2* __restrict__ emsg,
                                               float* __restrict__ dis,
                                               float* __restrict__ invc) {
  int b = blockIdx.x;
  __shared__ int hist[128], excl[128], cur[128];
  int t = threadIdx.x;
  if (t < 128) {
    hist[t] = 0;
    cur[t] = 0;
  }
  __syncthreads();
  int cnt = bcur[b] - b * BCAP;
  if (cnt > BCAP) cnt = BCAP;
  int tb = b * BCAP;
  int ob = bbase[b];
  for (int i = t; i < cnt; i += 256) {
    uint2 r = tmp[tb + i];
    atomicAdd(&hist[(r.x >> 16) & 127], 1);
  }
  __syncthreads();
  int myDeg = (t < 128) ? hist[t] : 0;
  for (int off = 1; off < 128; off <<= 1) {
    int x = 0;
    if (t < 128 && t >= off) x = hist[t - off];
    __syncthreads();
    if (t < 128) hist[t] += x;
    __syncthreads();
  }
  if (t < 128) {
    excl[t] = hist[t] - myDeg;
    int node = (b << 7) + t;
    if (node < NN) {
      rowptr[node] = ob + excl[t];
      dis[node] = rsqrtf((float)(myDeg + 1));
      invc[node] = (myDeg > 0) ? 1.0f / (float)myDeg : 1.0f;
    }
  }
  __syncthreads();
  for (int i = t; i < cnt; i += 256) {
    uint2 r = tmp[tb + i];
    int o = (r.x >> 16) & 127;
    int p = atomicAdd(&cur[o], 1);
    int pos = ob + excl[o] + p;
    int s = (int)(r.x & 0xffffu);
    csrc[pos] = s;
    emsg[pos] = make_uint2((uint32)s, r.y);
  }
}

// ---------------- GEMM via MFMA: Y[n,FOUT] = dis[row] * (X[n,128] @ W) ------
// The dis-scaling folds the GCN symmetric norm into the table so k_agg's
// inner loop is a pure sum of gathered rows.
template <int FOUT, bool IN_BF, bool OUT_BF>
__global__ __launch_bounds__(256) void k_gemm(const void* __restrict__ Xv,
                                              const float* __restrict__ W,
                                              const float* __restrict__ dis,
                                              void* __restrict__ Yv, int n) {
  const int NT = FOUT / 16;  // 16x16 col-tiles per wave
  __shared__ __align__(16) unsigned short Wt[FOUT][136];
  __shared__ __align__(16) unsigned short Xs[64][136];
  int t = threadIdx.x;
  int row0 = blockIdx.x * 64;
  for (int idx = t; idx < 128 * FOUT; idx += 256) {
    int k = idx / FOUT, col = idx % FOUT;
    Wt[col][k] = (unsigned short)f2bf(W[idx]);
  }
  if (IN_BF) {
    const uint32* Xb = (const uint32*)Xv;
    for (int idx = t; idx < 64 * 64; idx += 256) {
      int r = idx >> 6, c = idx & 63;
      uint32 v = (row0 + r < n) ? Xb[(size_t)(row0 + r) * 64 + c] : 0u;
      *(uint32*)&Xs[r][c * 2] = v;
    }
  } else {
    const float* Xf = (const float*)Xv;
    for (int idx = t; idx < 64 * 64; idx += 256) {
      int r = idx >> 6, c = idx & 63;
      float2 v = make_float2(0.f, 0.f);
      if (row0 + r < n) v = ((const float2*)(Xf + (size_t)(row0 + r) * 128))[c];
      *(uint32*)&Xs[r][c * 2] = pack2(v.x, v.y);
    }
  }
  __syncthreads();
  int lane = t & 63, wv = t >> 6;
  int mrow = lane & 15, q = lane >> 4;
  f32x4 acc[NT];
#pragma unroll
  for (int c = 0; c < NT; c++) acc[c] = (f32x4){0.f, 0.f, 0.f, 0.f};
#pragma unroll
  for (int kt = 0; kt < 4; kt++) {
    bf16x8 af = *(const bf16x8*)&Xs[wv * 16 + mrow][kt * 32 + q * 8];
#pragma unroll
    for (int c = 0; c < NT; c++) {
      bf16x8 bfg = *(const bf16x8*)&Wt[c * 16 + mrow][kt * 32 + q * 8];
      acc[c] = __builtin_amdgcn_mfma_f32_16x16x32_bf16(af, bfg, acc[c], 0, 0, 0);
    }
  }
  // D: col = lane&15, row = (lane>>4)*4 + reg
  float ds[4];
#pragma unroll
  for (int r = 0; r < 4; r++) {
    int rg = row0 + wv * 16 + q * 4 + r;
    ds[r] = (rg < n) ? dis[rg] : 0.f;
  }
#pragma unroll
  for (int c = 0; c < NT; c++) {
    int cg = c * 16 + mrow;
#pragma unroll
    for (int r = 0; r < 4; r++) {
      int rg = row0 + wv * 16 + q * 4 + r;
      if (rg < n) {
        float v = acc[c][r] * ds[r];
        if (OUT_BF)
          ((unsigned short*)Yv)[(size_t)rg * FOUT + cg] = (unsigned short)f2bf(v);
        else
          ((float*)Yv)[(size_t)rg * FOUT + cg] = v;
      }
    }
  }
}

// ---- GCN aggregation, bf16 scaled tables (F=128): H = dn*(Σ XWs[s] + XWs[node]) + b
__global__ __launch_bounds__(256) void k_agg_bf(const uint32* __restrict__ XWb,
                                                const float* __restrict__ dis,
                                                const int* __restrict__ rowptr,
                                                const int* __restrict__ csrc,
                                                const float* __restrict__ bias,
                                                uint32* __restrict__ Hb, int n) {
  int lane = threadIdx.x & 63;
  int node = blockIdx.x * 4 + (threadIdx.x >> 6);
  if (node >= n) return;
  float dn = dis[node];
  int beg = rowptr[node], end = rowptr[node + 1];
  float ax = 0.f, ay = 0.f;
  int i = beg;
  for (; i + 8 <= end; i += 8) {
    int s[8];
    uint32 p[8];
#pragma unroll
    for (int k = 0; k < 8; k++) s[k] = csrc[i + k];
#pragma unroll
    for (int k = 0; k < 8; k++) p[k] = XWb[(size_t)s[k] * 64 + lane];
#pragma unroll
    for (int k = 0; k < 8; k++) {
      ax += bflo(p[k]);
      ay += bfhi(p[k]);
    }
  }
  for (; i < end; i++) {
    uint32 p = XWb[(size_t)csrc[i] * 64 + lane];
    ax += bflo(p);
    ay += bfhi(p);
  }
  uint32 ps = XWb[(size_t)node * 64 + lane];
  float2 bb = ((const float2*)bias)[lane];
  float hx = dn * (ax + bflo(ps)) + bb.x;
  float hy = dn * (ay + bfhi(ps)) + bb.y;
  Hb[(size_t)node * 64 + lane] = pack2(hx, hy);
}

// -- mean-agg of h[src]+relu(ea*ew+eb), ReLU+LN epilogue, bf16 tables (F=128) --
__global__ __launch_bounds__(256) void k_msg_bf(const uint32* __restrict__ Hb,
                                                const float* __restrict__ ew,
                                                const float* __restrict__ eb,
                                                const int* __restrict__ rowptr,
                                                const uint2* __restrict__ emsg,
                                                const float* __restrict__ invc,
                                                const float* __restrict__ lng,
                                                const float* __restrict__ lnb,
                                                uint32* __restrict__ OUTb, int n) {
  int lane = threadIdx.x & 63;
  int node = blockIdx.x * 4 + (threadIdx.x >> 6);
  if (node >= n) return;
  int beg = rowptr[node], end = rowptr[node + 1];
  float2 w = ((const float2*)ew)[lane];
  float2 b = ((const float2*)eb)[lane];
  float ax = 0.f, ay = 0.f;
  int i = beg;
  for (; i + 8 <= end; i += 8) {
    uint2 m[8];
    uint32 p[8];
#pragma unroll
    for (int k = 0; k < 8; k++) m[k] = emsg[i + k];
#pragma unroll
    for (int k = 0; k < 8; k++) p[k] = Hb[(size_t)m[k].x * 64 + lane];
#pragma unroll
    for (int k = 0; k < 8; k++) {
      float a = __uint_as_float(m[k].y);
      ax += bflo(p[k]) + fmaxf(a * w.x + b.x, 0.f);
      ay += bfhi(p[k]) + fmaxf(a * w.y + b.y, 0.f);
    }
  }
  for (; i < end; i++) {
    uint2 m = emsg[i];
    uint32 p = Hb[(size_t)m.x * 64 + lane];
    float a = __uint_as_float(m.y);
    ax += bflo(p) + fmaxf(a * w.x + b.x, 0.f);
    ay += bfhi(p) + fmaxf(a * w.y + b.y, 0.f);
  }
  float ic = invc[node];
  float ox = fmaxf(ax * ic, 0.f);
  float oy = fmaxf(ay * ic, 0.f);
  float s1 = ox + oy;
  float s2 = ox * ox + oy * oy;
  for (int off = 32; off; off >>= 1) {
    s1 += __shfl_xor(s1, off, 64);
    s2 += __shfl_xor(s2, off, 64);
  }
  float mu = s1 * (1.f / 128.f);
  float var = s2 * (1.f / 128.f) - mu * mu;
  float r = rsqrtf(var + LN_EPS);
  float2 g = ((const float2*)lng)[lane];
  float2 bb = ((const float2*)lnb)[lane];
  ox = (ox - mu) * r * g.x + bb.x;
  oy = (oy - mu) * r * g.y + bb.y;
  OUTb[(size_t)node * 64 + lane] = pack2(ox, oy);
}

// ---------------- fp32 layer-2 kernels (F=64, output precision) ----------------
// F1 rows are already dis-scaled by the GEMM epilogue.
__global__ __launch_bounds__(256) void k_agg64(const float* __restrict__ XWs,
                                               const float* __restrict__ dis,
                                               const int* __restrict__ rowptr,
                                               const int* __restrict__ csrc,
                                               const float* __restrict__ bias,
                                               float* __restrict__ H, int n) {
  int lane = threadIdx.x & 63;
  int node = blockIdx.x * 4 + (threadIdx.x >> 6);
  if (node >= n) return;
  float dn = dis[node];
  int beg = rowptr[node], end = rowptr[node + 1];
  float acc = 0.f;
  int i = beg;
  for (; i + 8 <= end; i += 8) {
    int s[8];
    float p[8];
#pragma unroll
    for (int k = 0; k < 8; k++) s[k] = csrc[i + k];
#pragma unroll
    for (int k = 0; k < 8; k++) p[k] = XWs[(size_t)s[k] * 64 + lane];
#pragma unroll
    for (int k = 0; k < 8; k++) acc += p[k];
  }
  for (; i < end; i++) acc += XWs[(size_t)csrc[i] * 64 + lane];
  H[(size_t)node * 64 + lane] = dn * (acc + XWs[(size_t)node * 64 + lane]) + bias[lane];
}

__global__ __launch_bounds__(256) void k_msg64(const float* __restrict__ H,
                                               const float* __restrict__ ew,
                                               const float* __restrict__ eb,
                                               const int* __restrict__ rowptr,
                                               const uint2* __restrict__ emsg,
                                               const float* __restrict__ invc,
                                               float* __restrict__ OUT, int n) {
  int lane = threadIdx.x & 63;
  int node = blockIdx.x * 4 + (threadIdx.x >> 6);
  if (node >= n) return;
  int beg = rowptr[node], end = rowptr[node + 1];
  float w = ew[lane], b = eb[lane];
  float acc = 0.f;
  int i = beg;
  for (; i + 8 <= end; i += 8) {
    uint2 m[8];
    float p[8];
#pragma unroll
    for (int k = 0; k < 8; k++) m[k] = emsg[i + k];
#pragma unroll
    for (int k = 0; k < 8; k++) p[k] = H[(size_t)m[k].x * 64 + lane];
#pragma unroll
    for (int k = 0; k < 8; k++)
      acc += p[k] + fmaxf(__uint_as_float(m[k].y) * w + b, 0.f);
  }
  for (; i < end; i++) {
    uint2 m = emsg[i];
    acc += H[(size_t)m.x * 64 + lane] + fmaxf(__uint_as_float(m.y) * w + b, 0.f);
  }
  OUT[(size_t)node * 64 + lane] = acc * invc[node];
}

// ------- global mean pool ----------
#define POOL_BLOCKS 256
__global__ __launch_bounds__(256) void k_pool_partial(const float* __restrict__ H,
                                                      const int* __restrict__ batch,
                                                      float* __restrict__ Z, int n) {
  int lane = threadIdx.x & 63;
  int wid = blockIdx.x * 4 + (threadIdx.x >> 6);
  const int WAVES = POOL_BLOCKS * 4;
  int per = (n + WAVES - 1) / WAVES;
  int beg = wid * per;
  int end = beg + per;
  if (end > n) end = n;
  if (beg >= end) return;
  int g = batch[beg];
  float acc = 0.f;
  for (int i = beg; i < end; i++) {
    int gi = batch[i];
    if (gi != g) {
      atomicAdd(&Z[g * 64 + lane], acc);
      acc = 0.f;
      g = gi;
    }
    acc += H[(size_t)i * 64 + lane];
  }
  atomicAdd(&Z[g * 64 + lane], acc);
}

__global__ __launch_bounds__(64) void k_pool_div(float* __restrict__ Z,
                                                 const int* __restrict__ batch, int n) {
  int g = blockIdx.x;
  __shared__ int scnt;
  if (threadIdx.x == 0) {
    int lo = 0, hi = n;
    while (lo < hi) { int m = (lo + hi) >> 1; if (batch[m] < g) lo = m + 1; else hi = m; }
    int b0 = lo;
    lo = 0; hi = n;
    while (lo < hi) { int m = (lo + hi) >> 1; if (batch[m] < g + 1) lo = m + 1; else hi = m; }
    scnt = lo - b0;
  }
  __syncthreads();
  float c = (float)scnt;
  if (c < 1.f) c = 1.f;
  Z[g * 64 + threadIdx.x] /= c;
}

extern "C" void kernel_launch(void* const* d_in, const int* in_sizes, int n_in,
                              void* d_out, int out_size, void* d_ws, size_t ws_size,
                              hipStream_t stream) {
  const float* x = (const float*)d_in[0];
  const int* ei = (const int*)d_in[1];
  const float* ea = (const float*)d_in[2];
  const int* batch = (const int*)d_in[3];
  const float* gw0 = (const float*)d_in[4];
  const float* gb0 = (const float*)d_in[5];
  const float* ew0 = (const float*)d_in[6];
  const float* eb0 = (const float*)d_in[7];
  const float* lg0 = (const float*)d_in[8];
  const float* lb0 = (const float*)d_in[9];
  const float* gw1 = (const float*)d_in[10];
  const float* gb1 = (const float*)d_in[11];
  const float* ew1 = (const float*)d_in[12];
  const float* eb1 = (const float*)d_in[13];
  const float* lg1 = (const float*)d_in[14];
  const float* lb1 = (const float*)d_in[15];
  const float* gw2 = (const float*)d_in[16];
  const float* gb2 = (const float*)d_in[17];
  const float* ew2 = (const float*)d_in[18];
  const float* eb2 = (const float*)d_in[19];
  float* out = (float*)d_out;

  const int* src = ei;
  const int* dst = ei + NE;

  char* w = (char*)d_ws;
  size_t off = 0;
  auto alloc = [&](size_t bytes) -> void* {
    void* p = (void*)(w + off);
    off = (off + bytes + 255) & ~(size_t)255;
    return p;
  };
  int* rowptr = (int*)alloc((NN + 1) * sizeof(int));
  int* bcur = (int*)alloc(NBUK * sizeof(int));
  int* bbase = (int*)alloc((NBUK + 1) * sizeof(int));
  int* csrc = (int*)alloc(NE * sizeof(int));
  uint2* emsg = (uint2*)alloc(NE * sizeof(uint2));
  float* dis = (float*)alloc(NN * sizeof(float));
  float* invc = (float*)alloc(NN * sizeof(float));
  uint32* B1b = (uint32*)alloc((size_t)NN * 64 * sizeof(uint32));  // 128 bf16/row
  uint32* B2b = (uint32*)alloc((size_t)NN * 64 * sizeof(uint32));
  float* F1 = (float*)alloc((size_t)NN * 64 * sizeof(float));  // 12.8 MB
  float* F2 = (float*)alloc((size_t)NN * 64 * sizeof(float));
  uint2* tmp = (uint2*)F1;  // 9.6 MB needed; F1 dead until layer-2 GEMM

  // ---- CSR build (bucket counting sort) ----
  hipLaunchKernelGGL(k_init_bcur, dim3((NBUK + 255) / 256), dim3(256), 0, stream, bcur);
  hipLaunchKernelGGL(k_bucket, dim3((NE + EPB - 1) / EPB), dim3(1024), 0, stream, src, dst, ea,
                     bcur, tmp, NE);
  hipLaunchKernelGGL(k_bscan, dim3(1), dim3(512), 0, stream, bcur, bbase, rowptr);
  hipLaunchKernelGGL(k_bsort, dim3(NBUK), dim3(256), 0, stream, tmp, bcur, bbase, rowptr, csrc,
                     emsg, dis, invc);

  dim3 gemm_grid((NN + 63) / 64), tb(256);
  dim3 node_grid((NN + 3) / 4);

  // Layer 0: x(fp32) -> B1b(dis*xw bf16) -> B2b(h bf16) -> B1b(relu+LN bf16)
  hipLaunchKernelGGL((k_gemm<128, false, true>), gemm_grid, tb, 0, stream, x, gw0, dis, B1b, NN);
  hipLaunchKernelGGL(k_agg_bf, node_grid, tb, 0, stream, B1b, dis, rowptr, csrc, gb0, B2b, NN);
  hipLaunchKernelGGL(k_msg_bf, node_grid, tb, 0, stream, B2b, ew0, eb0, rowptr, emsg, invc,
                     lg0, lb0, B1b, NN);
  // Layer 1
  hipLaunchKernelGGL((k_gemm<128, true, true>), gemm_grid, tb, 0, stream, B1b, gw1, dis, B2b, NN);
  hipLaunchKernelGGL(k_agg_bf, node_grid, tb, 0, stream, B2b, dis, rowptr, csrc, gb1, B1b, NN);
  hipLaunchKernelGGL(k_msg_bf, node_grid, tb, 0, stream, B1b, ew1, eb1, rowptr, emsg, invc,
                     lg1, lb1, B2b, NN);
  // Layer 2 (fp32 out): B2b -> F1(dis*xw) -> F2(h) -> d_out   (tmp dead by now)
  hipLaunchKernelGGL((k_gemm<64, true, false>), gemm_grid, tb, 0, stream, B2b, gw2, dis, F1, NN);
  hipLaunchKernelGGL(k_agg64, node_grid, tb, 0, stream, F1, dis, rowptr, csrc, gb2, F2, NN);
  hipLaunchKernelGGL(k_msg64, node_grid, tb, 0, stream, F2, ew2, eb2, rowptr, emsg, invc,
                     out, NN);
  // Pool
  float* Z = out + (size_t)NN * 64;
  hipLaunchKernelGGL(k_zero_f, dim3((NG * 64 + 255) / 256), dim3(256), 0, stream, Z, NG * 64);
  hipLaunchKernelGGL(k_pool_partial, dim3(POOL_BLOCKS), tb, 0, stream, out, batch, Z, NN);
  hipLaunchKernelGGL(k_pool_div, dim3(NG), dim3(64), 0, stream, Z, batch, NN);
}

// Round 8
// 427.089 us; speedup vs baseline: 1.1113x; 1.1113x over previous
//
#include <hip/hip_runtime.h>

#define NN 50000
#define NE 800000
#define NG 64
#define HID 128
#define DOUT 64
#define LN_EPS 1e-5f
#define NBUK 391   // ceil(50000/128) coarse buckets of 128 dst nodes
#define BCAP 3072  // capacity per bucket
#define EPB 2048   // edges per k_bucket block (391 blocks -> full CU spread)

typedef unsigned int uint32;
typedef unsigned short ushort16;
typedef __attribute__((ext_vector_type(8))) short bf16x8;
typedef __attribute__((ext_vector_type(4))) float f32x4;

// ---- bf16 helpers (RNE pack, cheap unpack) ----
__device__ inline ushort16 f2bf(float f) {
  uint32 u = __float_as_uint(f);
  u += 0x7fffu + ((u >> 16) & 1u);
  return (ushort16)(u >> 16);
}
__device__ inline uint32 pack2(float x, float y) {
  return (uint32)f2bf(x) | ((uint32)f2bf(y) << 16);
}
__device__ inline float bflo(uint32 p) { return __uint_as_float(p << 16); }
__device__ inline float bfhi(uint32 p) { return __uint_as_float(p & 0xffff0000u); }

// ---- combined init: zero pool accumulators + init bucket cursors ----
__global__ __launch_bounds__(256) void k_init(float* __restrict__ Z, int* __restrict__ bcur) {
  int i = blockIdx.x * 256 + threadIdx.x;
  if (i < NG * 64) Z[i] = 0.f;
  if (i < NBUK) bcur[i] = i * BCAP;
}

// ---------------- CSR build: bucket counting sort ----------------
__global__ __launch_bounds__(1024) void k_bucket(const int* __restrict__ src,
                                                 const int* __restrict__ dst,
                                                 const float* __restrict__ ea,
                                                 int* __restrict__ bcur,
                                                 uint2* __restrict__ tmp, int e) {
  __shared__ int hist[NBUK], lbase[NBUK], lcur[NBUK];
  int t = threadIdx.x;
  for (int i = t; i < NBUK; i += 1024) {
    hist[i] = 0;
    lcur[i] = 0;
  }
  __syncthreads();
  int base_e = blockIdx.x * EPB;
  int dstv[EPB / 1024];
#pragma unroll
  for (int k = 0; k < EPB / 1024; k++) {
    int i = base_e + k * 1024 + t;
    int d = (i < e) ? dst[i] : -1;
    dstv[k] = d;
    if (d >= 0) atomicAdd(&hist[d >> 7], 1);
  }
  __syncthreads();
  for (int i = t; i < NBUK; i += 1024) {
    int c = hist[i];
    int b = 0;
    if (c > 0) b = atomicAdd(&bcur[i], c);
    lbase[i] = b;
  }
  __syncthreads();
#pragma unroll
  for (int k = 0; k < EPB / 1024; k++) {
    int i = base_e + k * 1024 + t;
    int d = dstv[k];
    if (d >= 0) {
      int b = d >> 7;
      int r = atomicAdd(&lcur[b], 1);
      int pos = lbase[b] + r;
      if (pos < (b + 1) * BCAP) {
        uint2 rec;
        rec.x = (uint32)(src[i] & 0xffff) | ((uint32)(d & 127) << 16);
        rec.y = __float_as_uint(ea[i]);
        tmp[pos] = rec;
      }
    }
  }
}

__global__ __launch_bounds__(512) void k_bscan(const int* __restrict__ bcur,
                                               int* __restrict__ bbase,
                                               int* __restrict__ rowptr) {
  __shared__ int s[512];
  int t = threadIdx.x;
  int v = 0;
  if (t < NBUK) {
    v = bcur[t] - t * BCAP;
    if (v > BCAP) v = BCAP;
  }
  s[t] = v;
  __syncthreads();
  for (int off = 1; off < 512; off <<= 1) {
    int x = (t >= off) ? s[t - off] : 0;
    __syncthreads();
    s[t] += x;
    __syncthreads();
  }
  if (t < NBUK) bbase[t] = s[t] - v;
  if (t == 511) {
    bbase[NBUK] = s[511];
    rowptr[NN] = s[511];
  }
}

// emits csrc (4B src) + emsg (uint2: src, edge_attr) + rowptr/dis/invc
__global__ __launch_bounds__(256) void k_bsort(const uint2* __restrict__ tmp,
                                               const int* __restrict__ bcur,
                                               const int* __restrict__ bbase,
                                               int* __restrict__ rowptr,
                                               int* __restrict__ csrc,
                                               uint2* __restrict__ emsg,
                                               float* __restrict__ dis,
                                               float* __restrict__ invc) {
  int b = blockIdx.x;
  __shared__ int hist[128], excl[128], cur[128];
  int t = threadIdx.x;
  if (t < 128) {
    hist[t] = 0;
    cur[t] = 0;
  }
  __syncthreads();
  int cnt = bcur[b] - b * BCAP;
  if (cnt > BCAP) cnt = BCAP;
  int tb = b * BCAP;
  int ob = bbase[b];
  for (int i = t; i < cnt; i += 256) {
    uint2 r = tmp[tb + i];
    atomicAdd(&hist[(r.x >> 16) & 127], 1);
  }
  __syncthreads();
  int myDeg = (t < 128) ? hist[t] : 0;
  for (int off = 1; off < 128; off <<= 1) {
    int x = 0;
    if (t < 128 && t >= off) x = hist[t - off];
    __syncthreads();
    if (t < 128) hist[t] += x;
    __syncthreads();
  }
  if (t < 128) {
    excl[t] = hist[t] - myDeg;
    int node = (b << 7) + t;
    if (node < NN) {
      rowptr[node] = ob + excl[t];
      dis[node] = rsqrtf((float)(myDeg + 1));
      invc[node] = (myDeg > 0) ? 1.0f / (float)myDeg : 1.0f;
    }
  }
  __syncthreads();
  for (int i = t; i < cnt; i += 256) {
    uint2 r = tmp[tb + i];
    int o = (r.x >> 16) & 127;
    int p = atomicAdd(&cur[o], 1);
    int pos = ob + excl[o] + p;
    int s = (int)(r.x & 0xffffu);
    csrc[pos] = s;
    emsg[pos] = make_uint2((uint32)s, r.y);
  }
}

// ---------------- GEMM via MFMA: Y[n,FOUT] = dis[row] * (X[n,128] @ W) ------
template <int FOUT, bool IN_BF, bool OUT_BF>
__global__ __launch_bounds__(256) void k_gemm(const void* __restrict__ Xv,
                                              const float* __restrict__ W,
                                              const float* __restrict__ dis,
                                              void* __restrict__ Yv, int n) {
  const int NT = FOUT / 16;  // 16x16 col-tiles per wave
  __shared__ __align__(16) unsigned short Wt[FOUT][136];
  __shared__ __align__(16) unsigned short Xs[64][136];
  int t = threadIdx.x;
  int row0 = blockIdx.x * 64;
  for (int idx = t; idx < 128 * FOUT; idx += 256) {
    int k = idx / FOUT, col = idx % FOUT;
    Wt[col][k] = (unsigned short)f2bf(W[idx]);
  }
  if (IN_BF) {
    const uint32* Xb = (const uint32*)Xv;
    for (int idx = t; idx < 64 * 64; idx += 256) {
      int r = idx >> 6, c = idx & 63;
      uint32 v = (row0 + r < n) ? Xb[(size_t)(row0 + r) * 64 + c] : 0u;
      *(uint32*)&Xs[r][c * 2] = v;
    }
  } else {
    const float* Xf = (const float*)Xv;
    for (int idx = t; idx < 64 * 64; idx += 256) {
      int r = idx >> 6, c = idx & 63;
      float2 v = make_float2(0.f, 0.f);
      if (row0 + r < n) v = ((const float2*)(Xf + (size_t)(row0 + r) * 128))[c];
      *(uint32*)&Xs[r][c * 2] = pack2(v.x, v.y);
    }
  }
  __syncthreads();
  int lane = t & 63, wv = t >> 6;
  int mrow = lane & 15, q = lane >> 4;
  f32x4 acc[NT];
#pragma unroll
  for (int c = 0; c < NT; c++) acc[c] = (f32x4){0.f, 0.f, 0.f, 0.f};
#pragma unroll
  for (int kt = 0; kt < 4; kt++) {
    bf16x8 af = *(const bf16x8*)&Xs[wv * 16 + mrow][kt * 32 + q * 8];
#pragma unroll
    for (int c = 0; c < NT; c++) {
      bf16x8 bfg = *(const bf16x8*)&Wt[c * 16 + mrow][kt * 32 + q * 8];
      acc[c] = __builtin_amdgcn_mfma_f32_16x16x32_bf16(af, bfg, acc[c], 0, 0, 0);
    }
  }
  // D: col = lane&15, row = (lane>>4)*4 + reg
  float ds[4];
#pragma unroll
  for (int r = 0; r < 4; r++) {
    int rg = row0 + wv * 16 + q * 4 + r;
    ds[r] = (rg < n) ? dis[rg] : 0.f;
  }
#pragma unroll
  for (int c = 0; c < NT; c++) {
    int cg = c * 16 + mrow;
#pragma unroll
    for (int r = 0; r < 4; r++) {
      int rg = row0 + wv * 16 + q * 4 + r;
      if (rg < n) {
        float v = acc[c][r] * ds[r];
        if (OUT_BF)
          ((unsigned short*)Yv)[(size_t)rg * FOUT + cg] = (unsigned short)f2bf(v);
        else
          ((float*)Yv)[(size_t)rg * FOUT + cg] = v;
      }
    }
  }
}

// ---- GCN agg, bf16 scaled table (F=128), half-wave: node per 32 lanes, 8B/lane
__global__ __launch_bounds__(256) void k_agg_bf(const uint2* __restrict__ XW2,
                                                const float* __restrict__ dis,
                                                const int* __restrict__ rowptr,
                                                const int* __restrict__ csrc,
                                                const float* __restrict__ bias,
                                                uint2* __restrict__ Hb2, int n) {
  int l = threadIdx.x & 31;
  int node = blockIdx.x * 8 + (threadIdx.x >> 5);
  if (node >= n) return;
  float dn = dis[node];
  int beg = rowptr[node], end = rowptr[node + 1];
  float a0 = 0.f, a1 = 0.f, a2 = 0.f, a3 = 0.f;
  int i = beg;
  for (; i + 8 <= end; i += 8) {
    int s[8];
    uint2 p[8];
#pragma unroll
    for (int k = 0; k < 8; k++) s[k] = csrc[i + k];
#pragma unroll
    for (int k = 0; k < 8; k++) p[k] = XW2[(size_t)s[k] * 32 + l];
#pragma unroll
    for (int k = 0; k < 8; k++) {
      a0 += bflo(p[k].x);
      a1 += bfhi(p[k].x);
      a2 += bflo(p[k].y);
      a3 += bfhi(p[k].y);
    }
  }
  for (; i < end; i++) {
    uint2 p = XW2[(size_t)csrc[i] * 32 + l];
    a0 += bflo(p.x);
    a1 += bfhi(p.x);
    a2 += bflo(p.y);
    a3 += bfhi(p.y);
  }
  uint2 ps = XW2[(size_t)node * 32 + l];
  float4 bb = ((const float4*)bias)[l];
  float h0 = dn * (a0 + bflo(ps.x)) + bb.x;
  float h1 = dn * (a1 + bfhi(ps.x)) + bb.y;
  float h2 = dn * (a2 + bflo(ps.y)) + bb.z;
  float h3 = dn * (a3 + bfhi(ps.y)) + bb.w;
  Hb2[(size_t)node * 32 + l] = make_uint2(pack2(h0, h1), pack2(h2, h3));
}

// -- mean-agg msg + ReLU + LN, bf16 tables (F=128), half-wave --
__global__ __launch_bounds__(256) void k_msg_bf(const uint2* __restrict__ Hb2,
                                                const float* __restrict__ ew,
                                                const float* __restrict__ eb,
                                                const int* __restrict__ rowptr,
                                                const uint2* __restrict__ emsg,
                                                const float* __restrict__ invc,
                                                const float* __restrict__ lng,
                                                const float* __restrict__ lnb,
                                                uint2* __restrict__ OUTb2, int n) {
  int l = threadIdx.x & 31;
  int node = blockIdx.x * 8 + (threadIdx.x >> 5);
  if (node >= n) return;
  int beg = rowptr[node], end = rowptr[node + 1];
  float4 w = ((const float4*)ew)[l];
  float4 b = ((const float4*)eb)[l];
  float a0 = 0.f, a1 = 0.f, a2 = 0.f, a3 = 0.f;
  int i = beg;
  for (; i + 8 <= end; i += 8) {
    uint2 m[8];
    uint2 p[8];
#pragma unroll
    for (int k = 0; k < 8; k++) m[k] = emsg[i + k];
#pragma unroll
    for (int k = 0; k < 8; k++) p[k] = Hb2[(size_t)m[k].x * 32 + l];
#pragma unroll
    for (int k = 0; k < 8; k++) {
      float a = __uint_as_float(m[k].y);
      a0 += bflo(p[k].x) + fmaxf(a * w.x + b.x, 0.f);
      a1 += bfhi(p[k].x) + fmaxf(a * w.y + b.y, 0.f);
      a2 += bflo(p[k].y) + fmaxf(a * w.z + b.z, 0.f);
      a3 += bfhi(p[k].y) + fmaxf(a * w.w + b.w, 0.f);
    }
  }
  for (; i < end; i++) {
    uint2 m = emsg[i];
    uint2 p = Hb2[(size_t)m.x * 32 + l];
    float a = __uint_as_float(m.y);
    a0 += bflo(p.x) + fmaxf(a * w.x + b.x, 0.f);
    a1 += bfhi(p.x) + fmaxf(a * w.y + b.y, 0.f);
    a2 += bflo(p.y) + fmaxf(a * w.z + b.z, 0.f);
    a3 += bfhi(p.y) + fmaxf(a * w.w + b.w, 0.f);
  }
  float ic = invc[node];
  float o0 = fmaxf(a0 * ic, 0.f), o1 = fmaxf(a1 * ic, 0.f);
  float o2 = fmaxf(a2 * ic, 0.f), o3 = fmaxf(a3 * ic, 0.f);
  float s1 = o0 + o1 + o2 + o3;
  float s2 = o0 * o0 + o1 * o1 + o2 * o2 + o3 * o3;
#pragma unroll
  for (int off = 16; off; off >>= 1) {
    s1 += __shfl_xor(s1, off, 64);
    s2 += __shfl_xor(s2, off, 64);
  }
  float mu = s1 * (1.f / 128.f);
  float var = s2 * (1.f / 128.f) - mu * mu;
  float r = rsqrtf(var + LN_EPS);
  float4 g = ((const float4*)lng)[l];
  float4 bb = ((const float4*)lnb)[l];
  o0 = (o0 - mu) * r * g.x + bb.x;
  o1 = (o1 - mu) * r * g.y + bb.y;
  o2 = (o2 - mu) * r * g.z + bb.z;
  o3 = (o3 - mu) * r * g.w + bb.w;
  OUTb2[(size_t)node * 32 + l] = make_uint2(pack2(o0, o1), pack2(o2, o3));
}

// ---- layer-2 GCN agg, bf16 table (F=64), half-wave: 32 lanes x 4B ----
__global__ __launch_bounds__(256) void k_agg64b(const uint32* __restrict__ XWb,
                                                const float* __restrict__ dis,
                                                const int* __restrict__ rowptr,
                                                const int* __restrict__ csrc,
                                                const float* __restrict__ bias,
                                                uint32* __restrict__ Hb, int n) {
  int l = threadIdx.x & 31;
  int node = blockIdx.x * 8 + (threadIdx.x >> 5);
  if (node >= n) return;
  float dn = dis[node];
  int beg = rowptr[node], end = rowptr[node + 1];
  float a0 = 0.f, a1 = 0.f;
  int i = beg;
  for (; i + 8 <= end; i += 8) {
    int s[8];
    uint32 p[8];
#pragma unroll
    for (int k = 0; k < 8; k++) s[k] = csrc[i + k];
#pragma unroll
    for (int k = 0; k < 8; k++) p[k] = XWb[(size_t)s[k] * 32 + l];
#pragma unroll
    for (int k = 0; k < 8; k++) {
      a0 += bflo(p[k]);
      a1 += bfhi(p[k]);
    }
  }
  for (; i < end; i++) {
    uint32 p = XWb[(size_t)csrc[i] * 32 + l];
    a0 += bflo(p);
    a1 += bfhi(p);
  }
  uint32 ps = XWb[(size_t)node * 32 + l];
  float2 bb = ((const float2*)bias)[l];
  float h0 = dn * (a0 + bflo(ps)) + bb.x;
  float h1 = dn * (a1 + bfhi(ps)) + bb.y;
  Hb[(size_t)node * 32 + l] = pack2(h0, h1);
}

// ---- layer-2 msg mean-agg, bf16 table in, fp32 out ----
__global__ __launch_bounds__(256) void k_msg64b(const uint32* __restrict__ Hb,
                                                const float* __restrict__ ew,
                                                const float* __restrict__ eb,
                                                const int* __restrict__ rowptr,
                                                const uint2* __restrict__ emsg,
                                                const float* __restrict__ invc,
                                                float* __restrict__ OUT, int n) {
  int l = threadIdx.x & 31;
  int node = blockIdx.x * 8 + (threadIdx.x >> 5);
  if (node >= n) return;
  int beg = rowptr[node], end = rowptr[node + 1];
  float2 w = ((const float2*)ew)[l];
  float2 b = ((const float2*)eb)[l];
  float a0 = 0.f, a1 = 0.f;
  int i = beg;
  for (; i + 8 <= end; i += 8) {
    uint2 m[8];
    uint32 p[8];
#pragma unroll
    for (int k = 0; k < 8; k++) m[k] = emsg[i + k];
#pragma unroll
    for (int k = 0; k < 8; k++) p[k] = Hb[(size_t)m[k].x * 32 + l];
#pragma unroll
    for (int k = 0; k < 8; k++) {
      float a = __uint_as_float(m[k].y);
      a0 += bflo(p[k]) + fmaxf(a * w.x + b.x, 0.f);
      a1 += bfhi(p[k]) + fmaxf(a * w.y + b.y, 0.f);
    }
  }
  for (; i < end; i++) {
    uint2 m = emsg[i];
    uint32 p = Hb[(size_t)m.x * 32 + l];
    float a = __uint_as_float(m.y);
    a0 += bflo(p) + fmaxf(a * w.x + b.x, 0.f);
    a1 += bfhi(p) + fmaxf(a * w.y + b.y, 0.f);
  }
  float ic = invc[node];
  ((float2*)OUT)[(size_t)node * 32 + l] = make_float2(a0 * ic, a1 * ic);
}

// ------- global mean pool ----------
#define POOL_BLOCKS 256
__global__ __launch_bounds__(256) void k_pool_partial(const float* __restrict__ H,
                                                      const int* __restrict__ batch,
                                                      float* __restrict__ Z, int n) {
  int lane = threadIdx.x & 63;
  int wid = blockIdx.x * 4 + (threadIdx.x >> 6);
  const int WAVES = POOL_BLOCKS * 4;
  int per = (n + WAVES - 1) / WAVES;
  int beg = wid * per;
  int end = beg + per;
  if (end > n) end = n;
  if (beg >= end) return;
  int g = batch[beg];
  float acc = 0.f;
  for (int i = beg; i < end; i++) {
    int gi = batch[i];
    if (gi != g) {
      atomicAdd(&Z[g * 64 + lane], acc);
      acc = 0.f;
      g = gi;
    }
    acc += H[(size_t)i * 64 + lane];
  }
  atomicAdd(&Z[g * 64 + lane], acc);
}

__global__ __launch_bounds__(64) void k_pool_div(float* __restrict__ Z,
                                                 const int* __restrict__ batch, int n) {
  int g = blockIdx.x;
  __shared__ int scnt;
  if (threadIdx.x == 0) {
    int lo = 0, hi = n;
    while (lo < hi) { int m = (lo + hi) >> 1; if (batch[m] < g) lo = m + 1; else hi = m; }
    int b0 = lo;
    lo = 0; hi = n;
    while (lo < hi) { int m = (lo + hi) >> 1; if (batch[m] < g + 1) lo = m + 1; else hi = m; }
    scnt = lo - b0;
  }
  __syncthreads();
  float c = (float)scnt;
  if (c < 1.f) c = 1.f;
  Z[g * 64 + threadIdx.x] /= c;
}

extern "C" void kernel_launch(void* const* d_in, const int* in_sizes, int n_in,
                              void* d_out, int out_size, void* d_ws, size_t ws_size,
                              hipStream_t stream) {
  const float* x = (const float*)d_in[0];
  const int* ei = (const int*)d_in[1];
  const float* ea = (const float*)d_in[2];
  const int* batch = (const int*)d_in[3];
  const float* gw0 = (const float*)d_in[4];
  const float* gb0 = (const float*)d_in[5];
  const float* ew0 = (const float*)d_in[6];
  const float* eb0 = (const float*)d_in[7];
  const float* lg0 = (const float*)d_in[8];
  const float* lb0 = (const float*)d_in[9];
  const float* gw1 = (const float*)d_in[10];
  const float* gb1 = (const float*)d_in[11];
  const float* ew1 = (const float*)d_in[12];
  const float* eb1 = (const float*)d_in[13];
  const float* lg1 = (const float*)d_in[14];
  const float* lb1 = (const float*)d_in[15];
  const float* gw2 = (const float*)d_in[16];
  const float* gb2 = (const float*)d_in[17];
  const float* ew2 = (const float*)d_in[18];
  const float* eb2 = (const float*)d_in[19];
  float* out = (float*)d_out;

  const int* src = ei;
  const int* dst = ei + NE;

  char* w = (char*)d_ws;
  size_t off = 0;
  auto alloc = [&](size_t bytes) -> void* {
    void* p = (void*)(w + off);
    off = (off + bytes + 255) & ~(size_t)255;
    return p;
  };
  int* rowptr = (int*)alloc((NN + 1) * sizeof(int));
  int* bcur = (int*)alloc(NBUK * sizeof(int));
  int* bbase = (int*)alloc((NBUK + 1) * sizeof(int));
  int* csrc = (int*)alloc(NE * sizeof(int));
  uint2* emsg = (uint2*)alloc(NE * sizeof(uint2));
  float* dis = (float*)alloc(NN * sizeof(float));
  float* invc = (float*)alloc(NN * sizeof(float));
  uint2* B1b = (uint2*)alloc((size_t)NN * 32 * sizeof(uint2));  // 128 bf16/row
  uint2* B2b = (uint2*)alloc((size_t)NN * 32 * sizeof(uint2));
  uint32* F1b = (uint32*)alloc((size_t)NN * 32 * sizeof(uint32));  // 64 bf16/row
  uint32* F2b = (uint32*)alloc((size_t)NN * 32 * sizeof(uint32));
  uint2* tmp = (uint2*)alloc((size_t)NBUK * BCAP * sizeof(uint2));  // 9.6 MB

  float* Z = out + (size_t)NN * 64;

  // ---- init + CSR build (bucket counting sort) ----
  hipLaunchKernelGGL(k_init, dim3((NG * 64 + 255) / 256), dim3(256), 0, stream, Z, bcur);
  hipLaunchKernelGGL(k_bucket, dim3((NE + EPB - 1) / EPB), dim3(1024), 0, stream, src, dst, ea,
                     bcur, tmp, NE);
  hipLaunchKernelGGL(k_bscan, dim3(1), dim3(512), 0, stream, bcur, bbase, rowptr);
  hipLaunchKernelGGL(k_bsort, dim3(NBUK), dim3(256), 0, stream, tmp, bcur, bbase, rowptr, csrc,
                     emsg, dis, invc);

  dim3 gemm_grid((NN + 63) / 64), tb(256);
  dim3 node_grid((NN + 7) / 8);

  // Layer 0: x(fp32) -> B1b(dis*xw bf16) -> B2b(h bf16) -> B1b(relu+LN bf16)
  hipLaunchKernelGGL((k_gemm<128, false, true>), gemm_grid, tb, 0, stream, x, gw0, dis, B1b, NN);
  hipLaunchKernelGGL(k_agg_bf, node_grid, tb, 0, stream, B1b, dis, rowptr, csrc, gb0, B2b, NN);
  hipLaunchKernelGGL(k_msg_bf, node_grid, tb, 0, stream, B2b, ew0, eb0, rowptr, emsg, invc,
                     lg0, lb0, B1b, NN);
  // Layer 1
  hipLaunchKernelGGL((k_gemm<128, true, true>), gemm_grid, tb, 0, stream, B1b, gw1, dis, B2b, NN);
  hipLaunchKernelGGL(k_agg_bf, node_grid, tb, 0, stream, B2b, dis, rowptr, csrc, gb1, B1b, NN);
  hipLaunchKernelGGL(k_msg_bf, node_grid, tb, 0, stream, B1b, ew1, eb1, rowptr, emsg, invc,
                     lg1, lb1, B2b, NN);
  // Layer 2: B2b -> F1b(dis*xw bf16) -> F2b(h bf16) -> d_out (fp32)
  hipLaunchKernelGGL((k_gemm<64, true, true>), gemm_grid, tb, 0, stream, B2b, gw2, dis, F1b, NN);
  hipLaunchKernelGGL(k_agg64b, node_grid, tb, 0, stream, F1b, dis, rowptr, csrc, gb2, F2b, NN);
  hipLaunchKernelGGL(k_msg64b, node_grid, tb, 0, stream, F2b, ew2, eb2, rowptr, emsg, invc,
                     out, NN);
  // Pool
  hipLaunchKernelGGL(k_pool_partial, dim3(POOL_BLOCKS), tb, 0, stream, out, batch, Z, NN);
  hipLaunchKernelGGL(k_pool_div, dim3(NG), dim3(64), 0, stream, Z, batch, NN);
}